// Round 6
// baseline (452.620 us; speedup 1.0000x reference)
//
#include <hip/hip_runtime.h>
#include <hip/hip_bf16.h>
#include <stdint.h>

// GCN 2-layer forward: out = A_hat @ relu(A_hat @ (X W1^T + b1)) W2^T + b2
// A_hat = D^-1/2 (A + I) D^-1/2, pull-based CSR aggregation (no fp32 atomics).
// GEMM epilogue pre-scales rows by dis[n] and stores H' in BF16 (halves gather
// bytes); aggregation gathers bf16, accumulates fp32.
// CSR build: edge_index unpacked to int32 once; count and fill passes are
// row-range partitioned into 8 XCD groups so cnt/cursor atomics and csr
// writes stay in ONE XCD's L2 (line ownership -> local fast-path atomics).

#define TPB 256

__device__ __forceinline__ float bf16lo(unsigned u) { return __uint_as_float(u << 16); }
__device__ __forceinline__ float bf16hi(unsigned u) { return __uint_as_float(u & 0xffff0000u); }
__device__ __forceinline__ unsigned short f2bf(float f) {
    unsigned u = __float_as_uint(f);
    return (unsigned short)((u + 0x7fff + ((u >> 16) & 1)) >> 16);  // RNE
}

// ---------------------------------------------------------------------------
// dtype probe: edge_index may arrive as int32 or int64. If int64 (values < 2^31,
// non-negative), every odd 32-bit word of the first 64 entries is 0.
__global__ void detect64_kernel(const int* __restrict__ ei32, int* __restrict__ flag) {
    if (threadIdx.x == 0 && blockIdx.x == 0) {
        int is64 = 1;
        for (int t = 0; t < 64; ++t) {
            if (ei32[2 * t + 1] != 0) { is64 = 0; break; }
        }
        *flag = is64;
    }
}

// ---------------------------------------------------------------------------
// unpack edge_index -> row32 / col32 (coalesced, one pass)
__global__ __launch_bounds__(TPB) void extract_kernel(const void* __restrict__ ei, int E,
                                                      int* __restrict__ row32,
                                                      int* __restrict__ col32,
                                                      const int* __restrict__ flag) {
    int e = blockIdx.x * TPB + threadIdx.x;
    if (e >= E) return;
    if (*flag) {
        const long long* p = (const long long*)ei;
        row32[e] = (int)p[e];
        col32[e] = (int)p[E + e];
    } else {
        const int* p = (const int*)ei;
        row32[e] = p[e];
        col32[e] = p[E + e];
    }
}

// ---------------------------------------------------------------------------
// Partitioned count: group g touches only rows in [N*g/8, N*(g+1)/8) so each
// cnt line is owned by one XCD -> local-L2 atomics, no cross-XCD ping-pong.
#define PART_CHUNKS 128
__global__ __launch_bounds__(TPB) void count_part_kernel(const int* __restrict__ row32, int E,
                                                         int* __restrict__ cnt, int N) {
    int g = blockIdx.x & 7;
    int chunk = blockIdx.x >> 3;
    int lo = (int)(((long long)N * g) >> 3);
    int hi = (int)(((long long)N * (g + 1)) >> 3);
    for (int e = chunk * TPB + threadIdx.x; e < E; e += PART_CHUNKS * TPB) {
        int r = row32[e];
        if (r >= lo && r < hi && (unsigned)r < (unsigned)N) atomicAdd(&cnt[r], 1);
    }
}

// ---------------------------------------------------------------------------
// scan part 1: per-1024-element tile local exclusive scan + tile totals; also dis[i]
__global__ __launch_bounds__(TPB) void scan1_kernel(const int* __restrict__ cnt,
                                                    int* __restrict__ offs,
                                                    int* __restrict__ bsums,
                                                    float* __restrict__ dis, int N) {
    __shared__ int sm[TPB];
    int tid = threadIdx.x;
    int base = blockIdx.x * 1024 + tid * 4;
    int4 v = make_int4(0, 0, 0, 0);
    if (base + 3 < N) {
        v = *(const int4*)(cnt + base);
    } else {
        if (base + 0 < N) v.x = cnt[base + 0];
        if (base + 1 < N) v.y = cnt[base + 1];
        if (base + 2 < N) v.z = cnt[base + 2];
        if (base + 3 < N) v.w = cnt[base + 3];
    }
    int tsum = v.x + v.y + v.z + v.w;
    sm[tid] = tsum;
    __syncthreads();
    for (int o = 1; o < TPB; o <<= 1) {
        int x = (tid >= o) ? sm[tid - o] : 0;
        __syncthreads();
        sm[tid] += x;
        __syncthreads();
    }
    int excl = sm[tid] - tsum;
    int4 o4;
    o4.x = excl;
    o4.y = o4.x + v.x;
    o4.z = o4.y + v.y;
    o4.w = o4.z + v.z;
    if (base + 3 < N) {
        *(int4*)(offs + base) = o4;
    } else {
        if (base + 0 < N) offs[base + 0] = o4.x;
        if (base + 1 < N) offs[base + 1] = o4.y;
        if (base + 2 < N) offs[base + 2] = o4.z;
        if (base + 3 < N) offs[base + 3] = o4.w;
    }
    if (tid == TPB - 1) bsums[blockIdx.x] = sm[TPB - 1];
    // dis = (deg+self)^{-1/2}
    int vv[4] = {v.x, v.y, v.z, v.w};
#pragma unroll
    for (int t = 0; t < 4; ++t) {
        int i = base + t;
        if (i < N) dis[i] = rsqrtf((float)vv[t] + 1.0f);
    }
}

// scan part 2: exclusive scan over tile sums (nb <= 128)
__global__ void scan2_kernel(int* __restrict__ bsums, int nb) {
    __shared__ int sm[128];
    int tid = threadIdx.x;
    int v = (tid < nb) ? bsums[tid] : 0;
    sm[tid] = v;
    __syncthreads();
    for (int o = 1; o < 128; o <<= 1) {
        int x = (tid >= o) ? sm[tid - o] : 0;
        __syncthreads();
        sm[tid] += x;
        __syncthreads();
    }
    if (tid < nb) bsums[tid] = sm[tid] - v;  // exclusive
}

// scan part 3: add tile offsets; also emit cursor = offs (fill's atomic base)
__global__ __launch_bounds__(TPB) void scan3_kernel(int* __restrict__ offs,
                                                    int* __restrict__ cursor,
                                                    const int* __restrict__ bsums, int N) {
    int add = bsums[blockIdx.x];
    int base = blockIdx.x * 1024 + threadIdx.x * 4;
    if (base + 3 < N) {
        int4 v = *(int4*)(offs + base);
        v.x += add; v.y += add; v.z += add; v.w += add;
        *(int4*)(offs + base) = v;
        *(int4*)(cursor + base) = v;
    } else {
#pragma unroll
        for (int t = 0; t < 4; ++t)
            if (base + t < N) {
                int v = offs[base + t] + add;
                offs[base + t] = v;
                cursor[base + t] = v;
            }
    }
}

// ---------------------------------------------------------------------------
// Partitioned CSR fill: group g handles rows in its 1/8 slice; cursor atomics
// and csr scattered writes stay in that XCD's L2.
__global__ __launch_bounds__(TPB) void fill_part_kernel(const int* __restrict__ row32,
                                                        const int* __restrict__ col32, int E,
                                                        int* __restrict__ cursor,
                                                        int* __restrict__ csr, int N) {
    int g = blockIdx.x & 7;
    int chunk = blockIdx.x >> 3;
    int lo = (int)(((long long)N * g) >> 3);
    int hi = (int)(((long long)N * (g + 1)) >> 3);
    for (int e = chunk * TPB + threadIdx.x; e < E; e += PART_CHUNKS * TPB) {
        int r = row32[e];
        if (r >= lo && r < hi && (unsigned)r < (unsigned)N) {
            int c = col32[e];
            if ((unsigned)c < (unsigned)N) {
                int pos = atomicAdd(&cursor[r], 1);
                csr[pos] = c;
            }
        }
    }
}

// ---------------------------------------------------------------------------
// Tiled fp32 GEMM: H[r, :] = dis[r] * (X[r,:] @ W^T + b),  K = 128, BN == OUTF.
// BM=128 nodes/block, BK=32. Both operands staged (transposed) in LDS; X read
// from global exactly once. 256 threads as 16x16; micro-tile 8 rows x (BN/16)
// cols per thread. Output stored as BF16 (row-major, BN cols).
template <int BN>
__global__ __launch_bounds__(256, 4) void gemm_tiled_kernel(const float* __restrict__ X,
                                                            const float* __restrict__ W,
                                                            const float* __restrict__ bias,
                                                            const float* __restrict__ dis,
                                                            unsigned short* __restrict__ Hb,
                                                            int N) {
    constexpr int BM = 128, BK = 32, K = 128;
    constexpr int BMp = BM + 4;          // padded LDS row stride
    constexpr int BNp = BN + 4;
    constexpr int CN = BN / 16;          // cols per thread: 8 (BN=128) or 4 (BN=64)
    __shared__ float Xs[BK * BMp];
    __shared__ float Ws[BK * BNp];

    const int tid = threadIdx.x;
    const int tx = tid & 15;             // col group
    const int ty = tid >> 4;             // row group
    const int r0 = blockIdx.x * BM;
    const int lrow = tid >> 3;           // 0..31 (staging row)
    const int kq = tid & 7;              // 0..7  (staging k-quad)

    float acc[8][CN];
#pragma unroll
    for (int r = 0; r < 8; ++r)
#pragma unroll
        for (int c = 0; c < CN; ++c) acc[r][c] = 0.0f;

    const float4* Xv = (const float4*)X;
    const float4* Wv = (const float4*)W;

    for (int k0 = 0; k0 < K; k0 += BK) {
        // ---- stage X tile (BM x BK), transposed to Xs[k][m]
#pragma unroll
        for (int p = 0; p < BM / 32; ++p) {
            int row = lrow + p * 32;
            int rg = r0 + row;
            if (rg >= N) rg = N - 1;     // clamp (stores are guarded)
            float4 v = Xv[(size_t)rg * (K / 4) + (k0 >> 2) + kq];
            Xs[(4 * kq + 0) * BMp + row] = v.x;
            Xs[(4 * kq + 1) * BMp + row] = v.y;
            Xs[(4 * kq + 2) * BMp + row] = v.z;
            Xs[(4 * kq + 3) * BMp + row] = v.w;
        }
        // ---- stage W tile (BN x BK), transposed to Ws[k][n]
#pragma unroll
        for (int p = 0; p < BN / 32; ++p) {
            int j = lrow + p * 32;
            float4 v = Wv[(size_t)j * (K / 4) + (k0 >> 2) + kq];
            Ws[(4 * kq + 0) * BNp + j] = v.x;
            Ws[(4 * kq + 1) * BNp + j] = v.y;
            Ws[(4 * kq + 2) * BNp + j] = v.z;
            Ws[(4 * kq + 3) * BNp + j] = v.w;
        }
        __syncthreads();

#pragma unroll 4
        for (int k = 0; k < BK; ++k) {
            float4 xa = *(const float4*)&Xs[k * BMp + 8 * ty];
            float4 xb = *(const float4*)&Xs[k * BMp + 8 * ty + 4];
            float4 wa = *(const float4*)&Ws[k * BNp + 4 * tx];
            float xr[8] = {xa.x, xa.y, xa.z, xa.w, xb.x, xb.y, xb.z, xb.w};
            float wc[CN];
            wc[0] = wa.x; wc[1] = wa.y; wc[2] = wa.z; wc[3] = wa.w;
            if (BN == 128) {
                float4 wb = *(const float4*)&Ws[k * BNp + 64 + 4 * tx];
                wc[4] = wb.x; wc[5] = wb.y; wc[6] = wb.z; wc[7] = wb.w;
            }
#pragma unroll
            for (int r = 0; r < 8; ++r)
#pragma unroll
                for (int c = 0; c < CN; ++c) acc[r][c] += xr[r] * wc[c];
        }
        __syncthreads();
    }

    // ---- epilogue: (+bias) * dis[row], pack bf16, store ushort4 per 4 cols
    float4 bva = *(const float4*)&bias[4 * tx];
    float4 bvb = make_float4(0.f, 0.f, 0.f, 0.f);
    if (BN == 128) bvb = *(const float4*)&bias[64 + 4 * tx];
#pragma unroll
    for (int r = 0; r < 8; ++r) {
        int row = r0 + 8 * ty + r;
        if (row < N) {
            float dn = dis[row];
            ushort4 oa;
            oa.x = f2bf((acc[r][0] + bva.x) * dn);
            oa.y = f2bf((acc[r][1] + bva.y) * dn);
            oa.z = f2bf((acc[r][2] + bva.z) * dn);
            oa.w = f2bf((acc[r][3] + bva.w) * dn);
            *(ushort4*)&Hb[(size_t)row * BN + 4 * tx] = oa;
            if (BN == 128) {
                ushort4 ob;
                ob.x = f2bf((acc[r][4] + bvb.x) * dn);
                ob.y = f2bf((acc[r][5] + bvb.y) * dn);
                ob.z = f2bf((acc[r][6] + bvb.z) * dn);
                ob.w = f2bf((acc[r][7] + bvb.w) * dn);
                *(ushort4*)&Hb[(size_t)row * BN + 64 + 4 * tx] = ob;
            }
        }
    }
}

// ---------------------------------------------------------------------------
// Pull aggregation over pre-scaled bf16 H' (H'[n] = dis[n]*(XW+b)[n]):
//   out[i] = dis[i] * (H'[i] + sum_e H'[col_e]),  optional relu.  fp32 out.
// One wave per node. Edge indices fetched coalesced 64-at-a-time, broadcast
// via shfl; in-loop global op is the bf16 H row gather, 8-way unrolled.
template <int F, bool RELU>
__global__ __launch_bounds__(TPB) void agg_kernel(const unsigned short* __restrict__ Hb,
                                                  const int* __restrict__ csr,
                                                  const int* __restrict__ offs,
                                                  const int* __restrict__ cnt,
                                                  const float* __restrict__ dis,
                                                  float* __restrict__ out, int N) {
    int w = (blockIdx.x * TPB + threadIdx.x) >> 6;
    if (w >= N) return;  // wave-uniform: whole wave exits together
    int lane = threadIdx.x & 63;
    float di = dis[w];
    int s = offs[w];
    int d = cnt[w];

    const unsigned* Hu = (const unsigned*)Hb;
    float2 acc;
    if (F == 128) {
        unsigned u = Hu[w * 64 + lane];
        acc.x = bf16lo(u);
        acc.y = bf16hi(u);
    } else {
        acc.x = __uint_as_float(((unsigned)Hb[w * 64 + lane]) << 16);
        acc.y = 0.0f;
    }

    for (int base = 0; base < d; base += 64) {
        int rem = d - base;
        if (rem > 64) rem = 64;
        int cl = (lane < rem) ? csr[s + base + lane] : 0;  // coalesced chunk load

        int e = 0;
        for (; e + 8 <= rem; e += 8) {
            int c0 = __shfl(cl, e + 0);
            int c1 = __shfl(cl, e + 1);
            int c2 = __shfl(cl, e + 2);
            int c3 = __shfl(cl, e + 3);
            int c4 = __shfl(cl, e + 4);
            int c5 = __shfl(cl, e + 5);
            int c6 = __shfl(cl, e + 6);
            int c7 = __shfl(cl, e + 7);
            if (F == 128) {
                unsigned u0 = Hu[c0 * 64 + lane];
                unsigned u1 = Hu[c1 * 64 + lane];
                unsigned u2 = Hu[c2 * 64 + lane];
                unsigned u3 = Hu[c3 * 64 + lane];
                unsigned u4 = Hu[c4 * 64 + lane];
                unsigned u5 = Hu[c5 * 64 + lane];
                unsigned u6 = Hu[c6 * 64 + lane];
                unsigned u7 = Hu[c7 * 64 + lane];
                acc.x += ((bf16lo(u0) + bf16lo(u1)) + (bf16lo(u2) + bf16lo(u3))) +
                         ((bf16lo(u4) + bf16lo(u5)) + (bf16lo(u6) + bf16lo(u7)));
                acc.y += ((bf16hi(u0) + bf16hi(u1)) + (bf16hi(u2) + bf16hi(u3))) +
                         ((bf16hi(u4) + bf16hi(u5)) + (bf16hi(u6) + bf16hi(u7)));
            } else {
                float h0 = __uint_as_float(((unsigned)Hb[c0 * 64 + lane]) << 16);
                float h1 = __uint_as_float(((unsigned)Hb[c1 * 64 + lane]) << 16);
                float h2 = __uint_as_float(((unsigned)Hb[c2 * 64 + lane]) << 16);
                float h3 = __uint_as_float(((unsigned)Hb[c3 * 64 + lane]) << 16);
                float h4 = __uint_as_float(((unsigned)Hb[c4 * 64 + lane]) << 16);
                float h5 = __uint_as_float(((unsigned)Hb[c5 * 64 + lane]) << 16);
                float h6 = __uint_as_float(((unsigned)Hb[c6 * 64 + lane]) << 16);
                float h7 = __uint_as_float(((unsigned)Hb[c7 * 64 + lane]) << 16);
                acc.x += ((h0 + h1) + (h2 + h3)) + ((h4 + h5) + (h6 + h7));
            }
        }
        for (; e < rem; ++e) {
            int c0 = __shfl(cl, e);
            if (F == 128) {
                unsigned u0 = Hu[c0 * 64 + lane];
                acc.x += bf16lo(u0);
                acc.y += bf16hi(u0);
            } else {
                acc.x += __uint_as_float(((unsigned)Hb[c0 * 64 + lane]) << 16);
            }
        }
    }

    acc.x *= di;
    acc.y *= di;
    if (RELU) { acc.x = fmaxf(acc.x, 0.f); acc.y = fmaxf(acc.y, 0.f); }
    if (F == 128) {
        ((float2*)out)[w * 64 + lane] = acc;  // cols 2*lane, 2*lane+1
    } else {
        out[w * 64 + lane] = acc.x;
    }
}

// ---------------------------------------------------------------------------
extern "C" void kernel_launch(void* const* d_in, const int* in_sizes, int n_in,
                              void* d_out, int out_size, void* d_ws, size_t ws_size,
                              hipStream_t stream) {
    const float* x  = (const float*)d_in[0];
    const void*  ei = d_in[1];
    const float* W1 = (const float*)d_in[3];
    const float* b1 = (const float*)d_in[4];
    const float* W2 = (const float*)d_in[5];
    const float* b2 = (const float*)d_in[6];
    float* out = (float*)d_out;

    const int IN = 128, HID = 128, OUT = 64;
    const int N = in_sizes[0] / IN;
    const int E = in_sizes[1] / 2;

    char* ws = (char*)d_ws;
    size_t off = 0;
    auto alloc = [&](size_t bytes) -> void* {
        void* p = (void*)(ws + off);
        off += (bytes + 255) & ~(size_t)255;
        return p;
    };
    int*   cnt    = (int*)alloc((size_t)N * 4);
    int*   offs   = (int*)alloc((size_t)N * 4);
    int*   cursor = (int*)alloc((size_t)N * 4);
    int*   bsums  = (int*)alloc(512);
    int*   flag   = (int*)alloc(256);
    float* dis    = (float*)alloc((size_t)N * 4);
    int*   row32  = (int*)alloc((size_t)E * 4);
    int*   col32  = (int*)alloc((size_t)E * 4);
    int*   csr    = (int*)alloc((size_t)E * 4);
    unsigned short* H1b = (unsigned short*)alloc((size_t)N * HID * 2);  // bf16
    float*          R1  = (float*)alloc((size_t)N * HID * 4);           // fp32
    unsigned short* H2b = H1b;  // reuse: H1b dead after agg1 (N*OUT*2 <= N*HID*2)

    hipMemsetAsync(cnt, 0, (size_t)N * 4, stream);

    detect64_kernel<<<1, 64, 0, stream>>>((const int*)ei, flag);

    int egrid = (E + TPB - 1) / TPB;
    extract_kernel<<<egrid, TPB, 0, stream>>>(ei, E, row32, col32, flag);

    count_part_kernel<<<8 * PART_CHUNKS, TPB, 0, stream>>>(row32, E, cnt, N);

    int nb = (N + 1023) / 1024;
    scan1_kernel<<<nb, TPB, 0, stream>>>(cnt, offs, bsums, dis, N);
    scan2_kernel<<<1, 128, 0, stream>>>(bsums, nb);
    scan3_kernel<<<nb, TPB, 0, stream>>>(offs, cursor, bsums, N);

    fill_part_kernel<<<8 * PART_CHUNKS, TPB, 0, stream>>>(row32, col32, E, cursor, csr, N);

    int ngrid = (N + 127) / 128;

    // layer 1: H1b = bf16(dis .* (X@W1^T + b1)) ; R1 = relu(dis .* (self + gather))
    gemm_tiled_kernel<128><<<ngrid, 256, 0, stream>>>(x, W1, b1, dis, H1b, N);
    agg_kernel<128, true><<<(N + 3) / 4, TPB, 0, stream>>>(H1b, csr, offs, cnt, dis, R1, N);

    // layer 2: H2b = bf16(dis .* (R1@W2^T + b2)) ; out = dis .* (self + gather)
    gemm_tiled_kernel<64><<<ngrid, 256, 0, stream>>>(R1, W2, b2, dis, H2b, N);
    agg_kernel<64, false><<<(N + 3) / 4, TPB, 0, stream>>>(H2b, csr, offs, cnt, dis, out, N);
}

// Round 7
// 451.569 us; speedup vs baseline: 1.0023x; 1.0023x over previous
//
#include <hip/hip_runtime.h>
#include <hip/hip_bf16.h>
#include <stdint.h>

// GCN 2-layer forward: out = A_hat @ relu(A_hat @ (X W1^T + b1)) W2^T + b2
// A_hat = D^-1/2 (A + I) D^-1/2, pull-based CSR aggregation (no fp32 atomics).
// GEMM epilogue pre-scales rows by dis[n] and stores H' in BF16 (halves gather
// bytes); aggregation gathers bf16, accumulates fp32.
// CSR build: edge_index unpacked to int32 once; count and fill passes are
// row-range partitioned into 8 XCD groups (atomics stay XCD-local) and 4-way
// unrolled (independent atomic chains) at full-occupancy grid.

#define TPB 256
#define PART_BLOCKS 2048   // 8 groups x 256 chunks; 8 blocks/CU -> 100% occ

__device__ __forceinline__ float bf16lo(unsigned u) { return __uint_as_float(u << 16); }
__device__ __forceinline__ float bf16hi(unsigned u) { return __uint_as_float(u & 0xffff0000u); }
__device__ __forceinline__ unsigned short f2bf(float f) {
    unsigned u = __float_as_uint(f);
    return (unsigned short)((u + 0x7fff + ((u >> 16) & 1)) >> 16);  // RNE
}

// ---------------------------------------------------------------------------
// dtype probe: edge_index may arrive as int32 or int64. If int64 (values < 2^31,
// non-negative), every odd 32-bit word of the first 64 entries is 0.
__global__ void detect64_kernel(const int* __restrict__ ei32, int* __restrict__ flag) {
    if (threadIdx.x == 0 && blockIdx.x == 0) {
        int is64 = 1;
        for (int t = 0; t < 64; ++t) {
            if (ei32[2 * t + 1] != 0) { is64 = 0; break; }
        }
        *flag = is64;
    }
}

// ---------------------------------------------------------------------------
// unpack edge_index -> row32 / col32 (coalesced, one pass)
__global__ __launch_bounds__(TPB) void extract_kernel(const void* __restrict__ ei, int E,
                                                      int* __restrict__ row32,
                                                      int* __restrict__ col32,
                                                      const int* __restrict__ flag) {
    int e = blockIdx.x * TPB + threadIdx.x;
    if (e >= E) return;
    if (*flag) {
        const long long* p = (const long long*)ei;
        row32[e] = (int)p[e];
        col32[e] = (int)p[E + e];
    } else {
        const int* p = (const int*)ei;
        row32[e] = p[e];
        col32[e] = p[E + e];
    }
}

// ---------------------------------------------------------------------------
// Partitioned count: group g touches only rows in [N*g/8, N*(g+1)/8) so each
// cnt line is owned by one XCD. int4 loads give 4 independent atomics/thread.
__global__ __launch_bounds__(TPB) void count_part_kernel(const int* __restrict__ row32, int E,
                                                         int* __restrict__ cnt, int N) {
    int g = blockIdx.x & 7;
    int chunk = blockIdx.x >> 3;
    int lo = (int)(((long long)N * g) >> 3);
    int hi = (int)(((long long)N * (g + 1)) >> 3);
    unsigned range = (unsigned)(hi - lo);
    int E4 = E >> 2;
    const int4* r4 = (const int4*)row32;
    int stride = (PART_BLOCKS / 8) * TPB;
    for (int i = chunk * TPB + threadIdx.x; i < E4; i += stride) {
        int4 v = r4[i];
        if ((unsigned)(v.x - lo) < range) atomicAdd(&cnt[v.x], 1);
        if ((unsigned)(v.y - lo) < range) atomicAdd(&cnt[v.y], 1);
        if ((unsigned)(v.z - lo) < range) atomicAdd(&cnt[v.z], 1);
        if ((unsigned)(v.w - lo) < range) atomicAdd(&cnt[v.w], 1);
    }
    // tail (E not multiple of 4)
    if (chunk == 0 && threadIdx.x < (E & 3)) {
        int r = row32[(E & ~3) + threadIdx.x];
        if ((unsigned)(r - lo) < range) atomicAdd(&cnt[r], 1);
    }
}

// ---------------------------------------------------------------------------
// scan part 1: per-1024-element tile local exclusive scan + tile totals; also dis[i]
__global__ __launch_bounds__(TPB) void scan1_kernel(const int* __restrict__ cnt,
                                                    int* __restrict__ offs,
                                                    int* __restrict__ bsums,
                                                    float* __restrict__ dis, int N) {
    __shared__ int sm[TPB];
    int tid = threadIdx.x;
    int base = blockIdx.x * 1024 + tid * 4;
    int4 v = make_int4(0, 0, 0, 0);
    if (base + 3 < N) {
        v = *(const int4*)(cnt + base);
    } else {
        if (base + 0 < N) v.x = cnt[base + 0];
        if (base + 1 < N) v.y = cnt[base + 1];
        if (base + 2 < N) v.z = cnt[base + 2];
        if (base + 3 < N) v.w = cnt[base + 3];
    }
    int tsum = v.x + v.y + v.z + v.w;
    sm[tid] = tsum;
    __syncthreads();
    for (int o = 1; o < TPB; o <<= 1) {
        int x = (tid >= o) ? sm[tid - o] : 0;
        __syncthreads();
        sm[tid] += x;
        __syncthreads();
    }
    int excl = sm[tid] - tsum;
    int4 o4;
    o4.x = excl;
    o4.y = o4.x + v.x;
    o4.z = o4.y + v.y;
    o4.w = o4.z + v.z;
    if (base + 3 < N) {
        *(int4*)(offs + base) = o4;
    } else {
        if (base + 0 < N) offs[base + 0] = o4.x;
        if (base + 1 < N) offs[base + 1] = o4.y;
        if (base + 2 < N) offs[base + 2] = o4.z;
        if (base + 3 < N) offs[base + 3] = o4.w;
    }
    if (tid == TPB - 1) bsums[blockIdx.x] = sm[TPB - 1];
    // dis = (deg+self)^{-1/2}
    int vv[4] = {v.x, v.y, v.z, v.w};
#pragma unroll
    for (int t = 0; t < 4; ++t) {
        int i = base + t;
        if (i < N) dis[i] = rsqrtf((float)vv[t] + 1.0f);
    }
}

// scan part 2: exclusive scan over tile sums (nb <= 128)
__global__ void scan2_kernel(int* __restrict__ bsums, int nb) {
    __shared__ int sm[128];
    int tid = threadIdx.x;
    int v = (tid < nb) ? bsums[tid] : 0;
    sm[tid] = v;
    __syncthreads();
    for (int o = 1; o < 128; o <<= 1) {
        int x = (tid >= o) ? sm[tid - o] : 0;
        __syncthreads();
        sm[tid] += x;
        __syncthreads();
    }
    if (tid < nb) bsums[tid] = sm[tid] - v;  // exclusive
}

// scan part 3: add tile offsets; also emit cursor = offs (fill's atomic base)
__global__ __launch_bounds__(TPB) void scan3_kernel(int* __restrict__ offs,
                                                    int* __restrict__ cursor,
                                                    const int* __restrict__ bsums, int N) {
    int add = bsums[blockIdx.x];
    int base = blockIdx.x * 1024 + threadIdx.x * 4;
    if (base + 3 < N) {
        int4 v = *(int4*)(offs + base);
        v.x += add; v.y += add; v.z += add; v.w += add;
        *(int4*)(offs + base) = v;
        *(int4*)(cursor + base) = v;
    } else {
#pragma unroll
        for (int t = 0; t < 4; ++t)
            if (base + t < N) {
                int v = offs[base + t] + add;
                offs[base + t] = v;
                cursor[base + t] = v;
            }
    }
}

// ---------------------------------------------------------------------------
// Partitioned CSR fill: group g handles rows in its 1/8 slice; cursor atomics
// and csr scattered writes stay in that XCD's L2. int4 loads -> 4 independent
// atomic->store chains per thread to hide the ~400cy atomic-return latency.
__global__ __launch_bounds__(TPB) void fill_part_kernel(const int* __restrict__ row32,
                                                        const int* __restrict__ col32, int E,
                                                        int* __restrict__ cursor,
                                                        int* __restrict__ csr, int N) {
    int g = blockIdx.x & 7;
    int chunk = blockIdx.x >> 3;
    int lo = (int)(((long long)N * g) >> 3);
    int hi = (int)(((long long)N * (g + 1)) >> 3);
    unsigned range = (unsigned)(hi - lo);
    unsigned uN = (unsigned)N;
    int E4 = E >> 2;
    const int4* r4 = (const int4*)row32;
    const int4* c4 = (const int4*)col32;
    int stride = (PART_BLOCKS / 8) * TPB;
    for (int i = chunk * TPB + threadIdx.x; i < E4; i += stride) {
        int4 r = r4[i];
        int4 c = c4[i];
        int p0 = -1, p1 = -1, p2 = -1, p3 = -1;
        if ((unsigned)(r.x - lo) < range && (unsigned)c.x < uN) p0 = atomicAdd(&cursor[r.x], 1);
        if ((unsigned)(r.y - lo) < range && (unsigned)c.y < uN) p1 = atomicAdd(&cursor[r.y], 1);
        if ((unsigned)(r.z - lo) < range && (unsigned)c.z < uN) p2 = atomicAdd(&cursor[r.z], 1);
        if ((unsigned)(r.w - lo) < range && (unsigned)c.w < uN) p3 = atomicAdd(&cursor[r.w], 1);
        if (p0 >= 0) csr[p0] = c.x;
        if (p1 >= 0) csr[p1] = c.y;
        if (p2 >= 0) csr[p2] = c.z;
        if (p3 >= 0) csr[p3] = c.w;
    }
    // tail
    if (chunk == 0 && threadIdx.x < (E & 3)) {
        int e = (E & ~3) + threadIdx.x;
        int r = row32[e];
        int c = col32[e];
        if ((unsigned)(r - lo) < range && (unsigned)c < uN) {
            int pos = atomicAdd(&cursor[r], 1);
            csr[pos] = c;
        }
    }
}

// ---------------------------------------------------------------------------
// Tiled fp32 GEMM: H[r, :] = dis[r] * (X[r,:] @ W^T + b),  K = 128, BN == OUTF.
// BM=128 nodes/block, BK=32. Both operands staged (transposed) in LDS; X read
// from global exactly once. 256 threads as 16x16; micro-tile 8 rows x (BN/16)
// cols per thread. Output stored as BF16 (row-major, BN cols).
template <int BN>
__global__ __launch_bounds__(256, 4) void gemm_tiled_kernel(const float* __restrict__ X,
                                                            const float* __restrict__ W,
                                                            const float* __restrict__ bias,
                                                            const float* __restrict__ dis,
                                                            unsigned short* __restrict__ Hb,
                                                            int N) {
    constexpr int BM = 128, BK = 32, K = 128;
    constexpr int BMp = BM + 4;          // padded LDS row stride
    constexpr int BNp = BN + 4;
    constexpr int CN = BN / 16;          // cols per thread: 8 (BN=128) or 4 (BN=64)
    __shared__ float Xs[BK * BMp];
    __shared__ float Ws[BK * BNp];

    const int tid = threadIdx.x;
    const int tx = tid & 15;             // col group
    const int ty = tid >> 4;             // row group
    const int r0 = blockIdx.x * BM;
    const int lrow = tid >> 3;           // 0..31 (staging row)
    const int kq = tid & 7;              // 0..7  (staging k-quad)

    float acc[8][CN];
#pragma unroll
    for (int r = 0; r < 8; ++r)
#pragma unroll
        for (int c = 0; c < CN; ++c) acc[r][c] = 0.0f;

    const float4* Xv = (const float4*)X;
    const float4* Wv = (const float4*)W;

    for (int k0 = 0; k0 < K; k0 += BK) {
        // ---- stage X tile (BM x BK), transposed to Xs[k][m]
#pragma unroll
        for (int p = 0; p < BM / 32; ++p) {
            int row = lrow + p * 32;
            int rg = r0 + row;
            if (rg >= N) rg = N - 1;     // clamp (stores are guarded)
            float4 v = Xv[(size_t)rg * (K / 4) + (k0 >> 2) + kq];
            Xs[(4 * kq + 0) * BMp + row] = v.x;
            Xs[(4 * kq + 1) * BMp + row] = v.y;
            Xs[(4 * kq + 2) * BMp + row] = v.z;
            Xs[(4 * kq + 3) * BMp + row] = v.w;
        }
        // ---- stage W tile (BN x BK), transposed to Ws[k][n]
#pragma unroll
        for (int p = 0; p < BN / 32; ++p) {
            int j = lrow + p * 32;
            float4 v = Wv[(size_t)j * (K / 4) + (k0 >> 2) + kq];
            Ws[(4 * kq + 0) * BNp + j] = v.x;
            Ws[(4 * kq + 1) * BNp + j] = v.y;
            Ws[(4 * kq + 2) * BNp + j] = v.z;
            Ws[(4 * kq + 3) * BNp + j] = v.w;
        }
        __syncthreads();

#pragma unroll 4
        for (int k = 0; k < BK; ++k) {
            float4 xa = *(const float4*)&Xs[k * BMp + 8 * ty];
            float4 xb = *(const float4*)&Xs[k * BMp + 8 * ty + 4];
            float4 wa = *(const float4*)&Ws[k * BNp + 4 * tx];
            float xr[8] = {xa.x, xa.y, xa.z, xa.w, xb.x, xb.y, xb.z, xb.w};
            float wc[CN];
            wc[0] = wa.x; wc[1] = wa.y; wc[2] = wa.z; wc[3] = wa.w;
            if (BN == 128) {
                float4 wb = *(const float4*)&Ws[k * BNp + 64 + 4 * tx];
                wc[4] = wb.x; wc[5] = wb.y; wc[6] = wb.z; wc[7] = wb.w;
            }
#pragma unroll
            for (int r = 0; r < 8; ++r)
#pragma unroll
                for (int c = 0; c < CN; ++c) acc[r][c] += xr[r] * wc[c];
        }
        __syncthreads();
    }

    // ---- epilogue: (+bias) * dis[row], pack bf16, store ushort4 per 4 cols
    float4 bva = *(const float4*)&bias[4 * tx];
    float4 bvb = make_float4(0.f, 0.f, 0.f, 0.f);
    if (BN == 128) bvb = *(const float4*)&bias[64 + 4 * tx];
#pragma unroll
    for (int r = 0; r < 8; ++r) {
        int row = r0 + 8 * ty + r;
        if (row < N) {
            float dn = dis[row];
            ushort4 oa;
            oa.x = f2bf((acc[r][0] + bva.x) * dn);
            oa.y = f2bf((acc[r][1] + bva.y) * dn);
            oa.z = f2bf((acc[r][2] + bva.z) * dn);
            oa.w = f2bf((acc[r][3] + bva.w) * dn);
            *(ushort4*)&Hb[(size_t)row * BN + 4 * tx] = oa;
            if (BN == 128) {
                ushort4 ob;
                ob.x = f2bf((acc[r][4] + bvb.x) * dn);
                ob.y = f2bf((acc[r][5] + bvb.y) * dn);
                ob.z = f2bf((acc[r][6] + bvb.z) * dn);
                ob.w = f2bf((acc[r][7] + bvb.w) * dn);
                *(ushort4*)&Hb[(size_t)row * BN + 64 + 4 * tx] = ob;
            }
        }
    }
}

// ---------------------------------------------------------------------------
// Pull aggregation over pre-scaled bf16 H' (H'[n] = dis[n]*(XW+b)[n]):
//   out[i] = dis[i] * (H'[i] + sum_e H'[col_e]),  optional relu.  fp32 out.
// One wave per node. Edge indices fetched coalesced 64-at-a-time, broadcast
// via shfl; in-loop global op is the bf16 H row gather, 8-way unrolled.
template <int F, bool RELU>
__global__ __launch_bounds__(TPB) void agg_kernel(const unsigned short* __restrict__ Hb,
                                                  const int* __restrict__ csr,
                                                  const int* __restrict__ offs,
                                                  const int* __restrict__ cnt,
                                                  const float* __restrict__ dis,
                                                  float* __restrict__ out, int N) {
    int w = (blockIdx.x * TPB + threadIdx.x) >> 6;
    if (w >= N) return;  // wave-uniform: whole wave exits together
    int lane = threadIdx.x & 63;
    float di = dis[w];
    int s = offs[w];
    int d = cnt[w];

    const unsigned* Hu = (const unsigned*)Hb;
    float2 acc;
    if (F == 128) {
        unsigned u = Hu[w * 64 + lane];
        acc.x = bf16lo(u);
        acc.y = bf16hi(u);
    } else {
        acc.x = __uint_as_float(((unsigned)Hb[w * 64 + lane]) << 16);
        acc.y = 0.0f;
    }

    for (int base = 0; base < d; base += 64) {
        int rem = d - base;
        if (rem > 64) rem = 64;
        int cl = (lane < rem) ? csr[s + base + lane] : 0;  // coalesced chunk load

        int e = 0;
        for (; e + 8 <= rem; e += 8) {
            int c0 = __shfl(cl, e + 0);
            int c1 = __shfl(cl, e + 1);
            int c2 = __shfl(cl, e + 2);
            int c3 = __shfl(cl, e + 3);
            int c4 = __shfl(cl, e + 4);
            int c5 = __shfl(cl, e + 5);
            int c6 = __shfl(cl, e + 6);
            int c7 = __shfl(cl, e + 7);
            if (F == 128) {
                unsigned u0 = Hu[c0 * 64 + lane];
                unsigned u1 = Hu[c1 * 64 + lane];
                unsigned u2 = Hu[c2 * 64 + lane];
                unsigned u3 = Hu[c3 * 64 + lane];
                unsigned u4 = Hu[c4 * 64 + lane];
                unsigned u5 = Hu[c5 * 64 + lane];
                unsigned u6 = Hu[c6 * 64 + lane];
                unsigned u7 = Hu[c7 * 64 + lane];
                acc.x += ((bf16lo(u0) + bf16lo(u1)) + (bf16lo(u2) + bf16lo(u3))) +
                         ((bf16lo(u4) + bf16lo(u5)) + (bf16lo(u6) + bf16lo(u7)));
                acc.y += ((bf16hi(u0) + bf16hi(u1)) + (bf16hi(u2) + bf16hi(u3))) +
                         ((bf16hi(u4) + bf16hi(u5)) + (bf16hi(u6) + bf16hi(u7)));
            } else {
                float h0 = __uint_as_float(((unsigned)Hb[c0 * 64 + lane]) << 16);
                float h1 = __uint_as_float(((unsigned)Hb[c1 * 64 + lane]) << 16);
                float h2 = __uint_as_float(((unsigned)Hb[c2 * 64 + lane]) << 16);
                float h3 = __uint_as_float(((unsigned)Hb[c3 * 64 + lane]) << 16);
                float h4 = __uint_as_float(((unsigned)Hb[c4 * 64 + lane]) << 16);
                float h5 = __uint_as_float(((unsigned)Hb[c5 * 64 + lane]) << 16);
                float h6 = __uint_as_float(((unsigned)Hb[c6 * 64 + lane]) << 16);
                float h7 = __uint_as_float(((unsigned)Hb[c7 * 64 + lane]) << 16);
                acc.x += ((h0 + h1) + (h2 + h3)) + ((h4 + h5) + (h6 + h7));
            }
        }
        for (; e < rem; ++e) {
            int c0 = __shfl(cl, e);
            if (F == 128) {
                unsigned u0 = Hu[c0 * 64 + lane];
                acc.x += bf16lo(u0);
                acc.y += bf16hi(u0);
            } else {
                acc.x += __uint_as_float(((unsigned)Hb[c0 * 64 + lane]) << 16);
            }
        }
    }

    acc.x *= di;
    acc.y *= di;
    if (RELU) { acc.x = fmaxf(acc.x, 0.f); acc.y = fmaxf(acc.y, 0.f); }
    if (F == 128) {
        ((float2*)out)[w * 64 + lane] = acc;  // cols 2*lane, 2*lane+1
    } else {
        out[w * 64 + lane] = acc.x;
    }
}

// ---------------------------------------------------------------------------
extern "C" void kernel_launch(void* const* d_in, const int* in_sizes, int n_in,
                              void* d_out, int out_size, void* d_ws, size_t ws_size,
                              hipStream_t stream) {
    const float* x  = (const float*)d_in[0];
    const void*  ei = d_in[1];
    const float* W1 = (const float*)d_in[3];
    const float* b1 = (const float*)d_in[4];
    const float* W2 = (const float*)d_in[5];
    const float* b2 = (const float*)d_in[6];
    float* out = (float*)d_out;

    const int IN = 128, HID = 128, OUT = 64;
    const int N = in_sizes[0] / IN;
    const int E = in_sizes[1] / 2;

    char* ws = (char*)d_ws;
    size_t off = 0;
    auto alloc = [&](size_t bytes) -> void* {
        void* p = (void*)(ws + off);
        off += (bytes + 255) & ~(size_t)255;
        return p;
    };
    int*   cnt    = (int*)alloc((size_t)N * 4);
    int*   offs   = (int*)alloc((size_t)N * 4);
    int*   cursor = (int*)alloc((size_t)N * 4);
    int*   bsums  = (int*)alloc(512);
    int*   flag   = (int*)alloc(256);
    float* dis    = (float*)alloc((size_t)N * 4);
    int*   row32  = (int*)alloc((size_t)E * 4);
    int*   col32  = (int*)alloc((size_t)E * 4);
    int*   csr    = (int*)alloc((size_t)E * 4);
    unsigned short* H1b = (unsigned short*)alloc((size_t)N * HID * 2);  // bf16
    float*          R1  = (float*)alloc((size_t)N * HID * 4);           // fp32
    unsigned short* H2b = H1b;  // reuse: H1b dead after agg1 (N*OUT*2 <= N*HID*2)

    hipMemsetAsync(cnt, 0, (size_t)N * 4, stream);

    detect64_kernel<<<1, 64, 0, stream>>>((const int*)ei, flag);

    int egrid = (E + TPB - 1) / TPB;
    extract_kernel<<<egrid, TPB, 0, stream>>>(ei, E, row32, col32, flag);

    count_part_kernel<<<PART_BLOCKS, TPB, 0, stream>>>(row32, E, cnt, N);

    int nb = (N + 1023) / 1024;
    scan1_kernel<<<nb, TPB, 0, stream>>>(cnt, offs, bsums, dis, N);
    scan2_kernel<<<1, 128, 0, stream>>>(bsums, nb);
    scan3_kernel<<<nb, TPB, 0, stream>>>(offs, cursor, bsums, N);

    fill_part_kernel<<<PART_BLOCKS, TPB, 0, stream>>>(row32, col32, E, cursor, csr, N);

    int ngrid = (N + 127) / 128;

    // layer 1: H1b = bf16(dis .* (X@W1^T + b1)) ; R1 = relu(dis .* (self + gather))
    gemm_tiled_kernel<128><<<ngrid, 256, 0, stream>>>(x, W1, b1, dis, H1b, N);
    agg_kernel<128, true><<<(N + 3) / 4, TPB, 0, stream>>>(H1b, csr, offs, cnt, dis, R1, N);

    // layer 2: H2b = bf16(dis .* (R1@W2^T + b2)) ; out = dis .* (self + gather)
    gemm_tiled_kernel<64><<<ngrid, 256, 0, stream>>>(R1, W2, b2, dis, H2b, N);
    agg_kernel<64, false><<<(N + 3) / 4, TPB, 0, stream>>>(H2b, csr, offs, cnt, dis, out, N);
}

// Round 8
// 342.286 us; speedup vs baseline: 1.3223x; 1.3193x over previous
//
#include <hip/hip_runtime.h>
#include <hip/hip_bf16.h>
#include <stdint.h>

// GCN 2-layer forward: out = A_hat @ relu(A_hat @ (X W1^T + b1)) W2^T + b2
// A_hat = D^-1/2 (A + I) D^-1/2, pull-based CSR aggregation.
// GEMM epilogue pre-scales rows by dis[n] and stores H' in BF16; aggregation
// gathers bf16, accumulates fp32.
// CSR build = two-level counting sort with ZERO global atomics (device-scope
// atomics on gfx950 are memory-side: ~32-64B HBM transaction each — measured
// WRITE_SIZE ~70MB for 1.6M atomics across R4-R7). All per-edge atomics are
// LDS-only; global positions come from per-block histograms + scans.

#define TPB 256
#define NBLK_C 256            // edge chunks (blocks) in hist/scatter passes
#define TPB_C 1024            // threads per chunk block
#define MAX_NB 2048           // max coarse buckets (N <= 262144)

__device__ __forceinline__ float bf16lo(unsigned u) { return __uint_as_float(u << 16); }
__device__ __forceinline__ float bf16hi(unsigned u) { return __uint_as_float(u & 0xffff0000u); }
__device__ __forceinline__ unsigned short f2bf(float f) {
    unsigned u = __float_as_uint(f);
    return (unsigned short)((u + 0x7fff + ((u >> 16) & 1)) >> 16);  // RNE
}

// ---------------------------------------------------------------------------
// dtype probe: edge_index may arrive as int32 or int64. If int64 (values < 2^31,
// non-negative), every odd 32-bit word of the first 64 entries is 0.
__global__ void detect64_kernel(const int* __restrict__ ei32, int* __restrict__ flag) {
    if (threadIdx.x == 0 && blockIdx.x == 0) {
        int is64 = 1;
        for (int t = 0; t < 64; ++t) {
            if (ei32[2 * t + 1] != 0) { is64 = 0; break; }
        }
        *flag = is64;
    }
}

// ---------------------------------------------------------------------------
// K1: unpack edge_index -> row32/col32 AND per-block coarse-bucket histogram
// (bucket = row >> 7). LDS atomics only; hist[bin*NBLK_C + b] written once.
__global__ __launch_bounds__(TPB_C) void hist_extract_kernel(const void* __restrict__ ei, int E,
                                                             int CH,
                                                             const int* __restrict__ flag,
                                                             int* __restrict__ row32,
                                                             int* __restrict__ col32,
                                                             int* __restrict__ hist,
                                                             int NB, int N) {
    __shared__ int h[MAX_NB];
    int tid = threadIdx.x;
    for (int bin = tid; bin < NB; bin += TPB_C) h[bin] = 0;
    __syncthreads();

    int b = blockIdx.x;
    int s = b * CH;
    int end = min(E, s + CH);
    int is64 = *flag;
    unsigned uN = (unsigned)N;
    if (is64) {
        const long long* p = (const long long*)ei;
        for (int e = s + tid; e < end; e += TPB_C) {
            int r = (int)p[e];
            int c = (int)p[E + e];
            row32[e] = r;
            col32[e] = c;
            if ((unsigned)r < uN && (unsigned)c < uN) atomicAdd(&h[r >> 7], 1);
        }
    } else {
        const int* p = (const int*)ei;
        for (int e = s + tid; e < end; e += TPB_C) {
            int r = p[e];
            int c = p[E + e];
            row32[e] = r;
            col32[e] = c;
            if ((unsigned)r < uN && (unsigned)c < uN) atomicAdd(&h[r >> 7], 1);
        }
    }
    __syncthreads();
    for (int bin = tid; bin < NB; bin += TPB_C) hist[bin * NBLK_C + b] = h[bin];
}

// ---------------------------------------------------------------------------
// K2: per-bucket exclusive scan across the NBLK_C block histograms (in place);
// emits binTotal[bin]. One block per bucket, TPB == NBLK_C.
__global__ __launch_bounds__(NBLK_C) void colscan_kernel(int* __restrict__ hist,
                                                         int* __restrict__ binTotal) {
    __shared__ int sm[NBLK_C];
    int bin = blockIdx.x;
    int tid = threadIdx.x;
    int v = hist[bin * NBLK_C + tid];
    sm[tid] = v;
    __syncthreads();
    for (int o = 1; o < NBLK_C; o <<= 1) {
        int x = (tid >= o) ? sm[tid - o] : 0;
        __syncthreads();
        sm[tid] += x;
        __syncthreads();
    }
    hist[bin * NBLK_C + tid] = sm[tid] - v;  // exclusive within bucket
    if (tid == NBLK_C - 1) binTotal[bin] = sm[NBLK_C - 1];
}

// ---------------------------------------------------------------------------
// K3: exclusive scan over bucket totals -> bucketStart.  NB <= 1024.
__global__ __launch_bounds__(1024) void binscan_kernel(const int* __restrict__ binTotal,
                                                       int* __restrict__ bucketStart, int NB) {
    __shared__ int sm[1024];
    int tid = threadIdx.x;
    int v = (tid < NB) ? binTotal[tid] : 0;
    sm[tid] = v;
    __syncthreads();
    for (int o = 1; o < 1024; o <<= 1) {
        int x = (tid >= o) ? sm[tid - o] : 0;
        __syncthreads();
        sm[tid] += x;
        __syncthreads();
    }
    if (tid < NB) bucketStart[tid] = sm[tid] - v;
}

// ---------------------------------------------------------------------------
// K4: place edges into coarse buckets. Per-block LDS cursors seeded from
// bucketStart + per-block exclusive prefix; packed = (col<<7) | (row&127).
__global__ __launch_bounds__(TPB_C) void scatter_kernel(const int* __restrict__ row32,
                                                        const int* __restrict__ col32, int E,
                                                        int CH,
                                                        const int* __restrict__ hist,
                                                        const int* __restrict__ bucketStart,
                                                        int* __restrict__ bucketed,
                                                        int NB, int N) {
    __shared__ int cur[MAX_NB];
    int tid = threadIdx.x;
    int b = blockIdx.x;
    for (int bin = tid; bin < NB; bin += TPB_C)
        cur[bin] = bucketStart[bin] + hist[bin * NBLK_C + b];
    __syncthreads();

    int s = b * CH;
    int end = min(E, s + CH);
    unsigned uN = (unsigned)N;
    for (int e = s + tid; e < end; e += TPB_C) {
        int r = row32[e];
        int c = col32[e];
        if ((unsigned)r < uN && (unsigned)c < uN) {
            int pos = atomicAdd(&cur[r >> 7], 1);
            bucketed[pos] = (c << 7) | (r & 127);
        }
    }
}

// ---------------------------------------------------------------------------
// K5: fine counting sort inside each 128-row bucket. Emits offs/cnt/dis for
// the bucket's rows and the final csr segment (all LDS atomics; coalesced-ish
// writes confined to one ~8KB L2-resident region per block).
__global__ __launch_bounds__(TPB) void finecsr_kernel(const int* __restrict__ bucketed,
                                                      const int* __restrict__ bucketStart,
                                                      const int* __restrict__ binTotal,
                                                      int* __restrict__ offs,
                                                      int* __restrict__ cnt,
                                                      float* __restrict__ dis,
                                                      int* __restrict__ csr, int N) {
    __shared__ int c128[128];
    __shared__ int cur128[128];
    __shared__ int sm[TPB];
    int bin = blockIdx.x;
    int tid = threadIdx.x;
    int s = bucketStart[bin];
    int m = binTotal[bin];

    if (tid < 128) c128[tid] = 0;
    __syncthreads();
    for (int i = tid; i < m; i += TPB) atomicAdd(&c128[bucketed[s + i] & 127], 1);
    __syncthreads();

    int v = (tid < 128) ? c128[tid] : 0;
    sm[tid] = v;
    __syncthreads();
    for (int o = 1; o < 128; o <<= 1) {
        int x = (tid >= o) ? sm[tid - o] : 0;
        __syncthreads();
        sm[tid] += x;
        __syncthreads();
    }
    if (tid < 128) {
        int excl = sm[tid] - v;
        int r = bin * 128 + tid;
        if (r < N) {
            offs[r] = s + excl;
            cnt[r] = v;
            dis[r] = rsqrtf((float)v + 1.0f);
        }
        cur128[tid] = s + excl;
    }
    __syncthreads();
    for (int i = tid; i < m; i += TPB) {
        int p = bucketed[s + i];
        int pos = atomicAdd(&cur128[p & 127], 1);
        csr[pos] = p >> 7;
    }
}

// ---------------------------------------------------------------------------
// Tiled fp32 GEMM: H[r, :] = dis[r] * (X[r,:] @ W^T + b),  K = 128, BN == OUTF.
// BM=128 nodes/block, BK=32. Both operands staged (transposed) in LDS; X read
// from global exactly once. 256 threads as 16x16; micro-tile 8 rows x (BN/16)
// cols per thread. Output stored as BF16 (row-major, BN cols).
template <int BN>
__global__ __launch_bounds__(256, 4) void gemm_tiled_kernel(const float* __restrict__ X,
                                                            const float* __restrict__ W,
                                                            const float* __restrict__ bias,
                                                            const float* __restrict__ dis,
                                                            unsigned short* __restrict__ Hb,
                                                            int N) {
    constexpr int BM = 128, BK = 32, K = 128;
    constexpr int BMp = BM + 4;          // padded LDS row stride
    constexpr int BNp = BN + 4;
    constexpr int CN = BN / 16;          // cols per thread: 8 (BN=128) or 4 (BN=64)
    __shared__ float Xs[BK * BMp];
    __shared__ float Ws[BK * BNp];

    const int tid = threadIdx.x;
    const int tx = tid & 15;             // col group
    const int ty = tid >> 4;             // row group
    const int r0 = blockIdx.x * BM;
    const int lrow = tid >> 3;           // 0..31 (staging row)
    const int kq = tid & 7;              // 0..7  (staging k-quad)

    float acc[8][CN];
#pragma unroll
    for (int r = 0; r < 8; ++r)
#pragma unroll
        for (int c = 0; c < CN; ++c) acc[r][c] = 0.0f;

    const float4* Xv = (const float4*)X;
    const float4* Wv = (const float4*)W;

    for (int k0 = 0; k0 < K; k0 += BK) {
        // ---- stage X tile (BM x BK), transposed to Xs[k][m]
#pragma unroll
        for (int p = 0; p < BM / 32; ++p) {
            int row = lrow + p * 32;
            int rg = r0 + row;
            if (rg >= N) rg = N - 1;     // clamp (stores are guarded)
            float4 v = Xv[(size_t)rg * (K / 4) + (k0 >> 2) + kq];
            Xs[(4 * kq + 0) * BMp + row] = v.x;
            Xs[(4 * kq + 1) * BMp + row] = v.y;
            Xs[(4 * kq + 2) * BMp + row] = v.z;
            Xs[(4 * kq + 3) * BMp + row] = v.w;
        }
        // ---- stage W tile (BN x BK), transposed to Ws[k][n]
#pragma unroll
        for (int p = 0; p < BN / 32; ++p) {
            int j = lrow + p * 32;
            float4 v = Wv[(size_t)j * (K / 4) + (k0 >> 2) + kq];
            Ws[(4 * kq + 0) * BNp + j] = v.x;
            Ws[(4 * kq + 1) * BNp + j] = v.y;
            Ws[(4 * kq + 2) * BNp + j] = v.z;
            Ws[(4 * kq + 3) * BNp + j] = v.w;
        }
        __syncthreads();

#pragma unroll 4
        for (int k = 0; k < BK; ++k) {
            float4 xa = *(const float4*)&Xs[k * BMp + 8 * ty];
            float4 xb = *(const float4*)&Xs[k * BMp + 8 * ty + 4];
            float4 wa = *(const float4*)&Ws[k * BNp + 4 * tx];
            float xr[8] = {xa.x, xa.y, xa.z, xa.w, xb.x, xb.y, xb.z, xb.w};
            float wc[CN];
            wc[0] = wa.x; wc[1] = wa.y; wc[2] = wa.z; wc[3] = wa.w;
            if (BN == 128) {
                float4 wb = *(const float4*)&Ws[k * BNp + 64 + 4 * tx];
                wc[4] = wb.x; wc[5] = wb.y; wc[6] = wb.z; wc[7] = wb.w;
            }
#pragma unroll
            for (int r = 0; r < 8; ++r)
#pragma unroll
                for (int c = 0; c < CN; ++c) acc[r][c] += xr[r] * wc[c];
        }
        __syncthreads();
    }

    // ---- epilogue: (+bias) * dis[row], pack bf16, store ushort4 per 4 cols
    float4 bva = *(const float4*)&bias[4 * tx];
    float4 bvb = make_float4(0.f, 0.f, 0.f, 0.f);
    if (BN == 128) bvb = *(const float4*)&bias[64 + 4 * tx];
#pragma unroll
    for (int r = 0; r < 8; ++r) {
        int row = r0 + 8 * ty + r;
        if (row < N) {
            float dn = dis[row];
            ushort4 oa;
            oa.x = f2bf((acc[r][0] + bva.x) * dn);
            oa.y = f2bf((acc[r][1] + bva.y) * dn);
            oa.z = f2bf((acc[r][2] + bva.z) * dn);
            oa.w = f2bf((acc[r][3] + bva.w) * dn);
            *(ushort4*)&Hb[(size_t)row * BN + 4 * tx] = oa;
            if (BN == 128) {
                ushort4 ob;
                ob.x = f2bf((acc[r][4] + bvb.x) * dn);
                ob.y = f2bf((acc[r][5] + bvb.y) * dn);
                ob.z = f2bf((acc[r][6] + bvb.z) * dn);
                ob.w = f2bf((acc[r][7] + bvb.w) * dn);
                *(ushort4*)&Hb[(size_t)row * BN + 64 + 4 * tx] = ob;
            }
        }
    }
}

// ---------------------------------------------------------------------------
// Pull aggregation over pre-scaled bf16 H' (H'[n] = dis[n]*(XW+b)[n]):
//   out[i] = dis[i] * (H'[i] + sum_e H'[col_e]),  optional relu.  fp32 out.
// One wave per node. Edge indices fetched coalesced 64-at-a-time, broadcast
// via shfl; in-loop global op is the bf16 H row gather, 8-way unrolled.
template <int F, bool RELU>
__global__ __launch_bounds__(TPB) void agg_kernel(const unsigned short* __restrict__ Hb,
                                                  const int* __restrict__ csr,
                                                  const int* __restrict__ offs,
                                                  const int* __restrict__ cnt,
                                                  const float* __restrict__ dis,
                                                  float* __restrict__ out, int N) {
    int w = (blockIdx.x * TPB + threadIdx.x) >> 6;
    if (w >= N) return;  // wave-uniform: whole wave exits together
    int lane = threadIdx.x & 63;
    float di = dis[w];
    int s = offs[w];
    int d = cnt[w];

    const unsigned* Hu = (const unsigned*)Hb;
    float2 acc;
    if (F == 128) {
        unsigned u = Hu[w * 64 + lane];
        acc.x = bf16lo(u);
        acc.y = bf16hi(u);
    } else {
        acc.x = __uint_as_float(((unsigned)Hb[w * 64 + lane]) << 16);
        acc.y = 0.0f;
    }

    for (int base = 0; base < d; base += 64) {
        int rem = d - base;
        if (rem > 64) rem = 64;
        int cl = (lane < rem) ? csr[s + base + lane] : 0;  // coalesced chunk load

        int e = 0;
        for (; e + 8 <= rem; e += 8) {
            int c0 = __shfl(cl, e + 0);
            int c1 = __shfl(cl, e + 1);
            int c2 = __shfl(cl, e + 2);
            int c3 = __shfl(cl, e + 3);
            int c4 = __shfl(cl, e + 4);
            int c5 = __shfl(cl, e + 5);
            int c6 = __shfl(cl, e + 6);
            int c7 = __shfl(cl, e + 7);
            if (F == 128) {
                unsigned u0 = Hu[c0 * 64 + lane];
                unsigned u1 = Hu[c1 * 64 + lane];
                unsigned u2 = Hu[c2 * 64 + lane];
                unsigned u3 = Hu[c3 * 64 + lane];
                unsigned u4 = Hu[c4 * 64 + lane];
                unsigned u5 = Hu[c5 * 64 + lane];
                unsigned u6 = Hu[c6 * 64 + lane];
                unsigned u7 = Hu[c7 * 64 + lane];
                acc.x += ((bf16lo(u0) + bf16lo(u1)) + (bf16lo(u2) + bf16lo(u3))) +
                         ((bf16lo(u4) + bf16lo(u5)) + (bf16lo(u6) + bf16lo(u7)));
                acc.y += ((bf16hi(u0) + bf16hi(u1)) + (bf16hi(u2) + bf16hi(u3))) +
                         ((bf16hi(u4) + bf16hi(u5)) + (bf16hi(u6) + bf16hi(u7)));
            } else {
                float h0 = __uint_as_float(((unsigned)Hb[c0 * 64 + lane]) << 16);
                float h1 = __uint_as_float(((unsigned)Hb[c1 * 64 + lane]) << 16);
                float h2 = __uint_as_float(((unsigned)Hb[c2 * 64 + lane]) << 16);
                float h3 = __uint_as_float(((unsigned)Hb[c3 * 64 + lane]) << 16);
                float h4 = __uint_as_float(((unsigned)Hb[c4 * 64 + lane]) << 16);
                float h5 = __uint_as_float(((unsigned)Hb[c5 * 64 + lane]) << 16);
                float h6 = __uint_as_float(((unsigned)Hb[c6 * 64 + lane]) << 16);
                float h7 = __uint_as_float(((unsigned)Hb[c7 * 64 + lane]) << 16);
                acc.x += ((h0 + h1) + (h2 + h3)) + ((h4 + h5) + (h6 + h7));
            }
        }
        for (; e < rem; ++e) {
            int c0 = __shfl(cl, e);
            if (F == 128) {
                unsigned u0 = Hu[c0 * 64 + lane];
                acc.x += bf16lo(u0);
                acc.y += bf16hi(u0);
            } else {
                acc.x += __uint_as_float(((unsigned)Hb[c0 * 64 + lane]) << 16);
            }
        }
    }

    acc.x *= di;
    acc.y *= di;
    if (RELU) { acc.x = fmaxf(acc.x, 0.f); acc.y = fmaxf(acc.y, 0.f); }
    if (F == 128) {
        ((float2*)out)[w * 64 + lane] = acc;  // cols 2*lane, 2*lane+1
    } else {
        out[w * 64 + lane] = acc.x;
    }
}

// ---------------------------------------------------------------------------
extern "C" void kernel_launch(void* const* d_in, const int* in_sizes, int n_in,
                              void* d_out, int out_size, void* d_ws, size_t ws_size,
                              hipStream_t stream) {
    const float* x  = (const float*)d_in[0];
    const void*  ei = d_in[1];
    const float* W1 = (const float*)d_in[3];
    const float* b1 = (const float*)d_in[4];
    const float* W2 = (const float*)d_in[5];
    const float* b2 = (const float*)d_in[6];
    float* out = (float*)d_out;

    const int IN = 128, HID = 128, OUT = 64;
    const int N = in_sizes[0] / IN;
    const int E = in_sizes[1] / 2;
    const int NB = (N + 127) >> 7;                 // coarse buckets (rows/128)
    const int CH = (E + NBLK_C - 1) / NBLK_C;      // edges per chunk block

    char* ws = (char*)d_ws;
    size_t off = 0;
    auto alloc = [&](size_t bytes) -> void* {
        void* p = (void*)(ws + off);
        off += (bytes + 255) & ~(size_t)255;
        return p;
    };
    int*   flag     = (int*)alloc(256);
    int*   cnt      = (int*)alloc((size_t)N * 4);
    int*   offs     = (int*)alloc((size_t)N * 4);
    float* dis      = (float*)alloc((size_t)N * 4);
    int*   row32    = (int*)alloc((size_t)E * 4);
    int*   col32    = (int*)alloc((size_t)E * 4);
    int*   bucketed = (int*)alloc((size_t)E * 4);
    int*   csr      = (int*)alloc((size_t)E * 4);
    int*   hist     = (int*)alloc((size_t)NB * NBLK_C * 4);
    int*   binTotal = (int*)alloc((size_t)NB * 4);
    int*   bStart   = (int*)alloc((size_t)NB * 4);
    unsigned short* H1b = (unsigned short*)alloc((size_t)N * HID * 2);  // bf16
    float*          R1  = (float*)alloc((size_t)N * HID * 4);           // fp32
    unsigned short* H2b = H1b;  // reuse: H1b dead after agg1

    detect64_kernel<<<1, 64, 0, stream>>>((const int*)ei, flag);

    // ---- CSR build: counting sort, zero global atomics
    hist_extract_kernel<<<NBLK_C, TPB_C, 0, stream>>>(ei, E, CH, flag, row32, col32,
                                                      hist, NB, N);
    colscan_kernel<<<NB, NBLK_C, 0, stream>>>(hist, binTotal);
    binscan_kernel<<<1, 1024, 0, stream>>>(binTotal, bStart, NB);
    scatter_kernel<<<NBLK_C, TPB_C, 0, stream>>>(row32, col32, E, CH, hist, bStart,
                                                 bucketed, NB, N);
    finecsr_kernel<<<NB, TPB, 0, stream>>>(bucketed, bStart, binTotal,
                                           offs, cnt, dis, csr, N);

    int ngrid = (N + 127) / 128;

    // layer 1: H1b = bf16(dis .* (X@W1^T + b1)) ; R1 = relu(dis .* (self + gather))
    gemm_tiled_kernel<128><<<ngrid, 256, 0, stream>>>(x, W1, b1, dis, H1b, N);
    agg_kernel<128, true><<<(N + 3) / 4, TPB, 0, stream>>>(H1b, csr, offs, cnt, dis, R1, N);

    // layer 2: H2b = bf16(dis .* (R1@W2^T + b2)) ; out = dis .* (self + gather)
    gemm_tiled_kernel<64><<<ngrid, 256, 0, stream>>>(R1, W2, b2, dis, H2b, N);
    agg_kernel<64, false><<<(N + 3) / 4, TPB, 0, stream>>>(H2b, csr, offs, cnt, dis, out, N);
}

// Round 9
// 299.692 us; speedup vs baseline: 1.5103x; 1.1421x over previous
//
#include <hip/hip_runtime.h>
#include <hip/hip_bf16.h>
#include <stdint.h>

// GCN 2-layer forward: out = A_hat @ relu(A_hat @ (X W1^T + b1)) W2^T + b2
// A_hat = D^-1/2 (A + I) D^-1/2, pull-based CSR aggregation.
// GEMMs use bf16 MFMA (16x16x32), fp32 accumulate; epilogue pre-scales rows by
// dis[n] and stores H' in BF16. Aggregation gathers bf16, accumulates fp32;
// agg1 emits R1 in bf16 (gemm2 consumes bf16 directly).
// CSR build = two-level counting sort with ZERO global atomics (device-scope
// atomics on gfx950 are memory-side: ~32-64B HBM transaction each — measured
// WRITE_SIZE ~70MB for 1.6M atomics across R4-R7). All per-edge atomics LDS.

#define TPB 256
#define NBLK_C 256            // edge chunks (blocks) in hist/scatter passes
#define TPB_C 1024            // threads per chunk block
#define MAX_NB 2048           // max coarse buckets (N <= 262144)

typedef __attribute__((ext_vector_type(8))) __bf16 bf16x8;
typedef __attribute__((ext_vector_type(4))) float f32x4;

__device__ __forceinline__ float bf16lo(unsigned u) { return __uint_as_float(u << 16); }
__device__ __forceinline__ float bf16hi(unsigned u) { return __uint_as_float(u & 0xffff0000u); }
__device__ __forceinline__ unsigned short f2bf(float f) {
    unsigned u = __float_as_uint(f);
    return (unsigned short)((u + 0x7fff + ((u >> 16) & 1)) >> 16);  // RNE
}

// ---------------------------------------------------------------------------
// dtype probe: edge_index may arrive as int32 or int64. If int64 (values < 2^31,
// non-negative), every odd 32-bit word of the first 64 entries is 0.
__global__ void detect64_kernel(const int* __restrict__ ei32, int* __restrict__ flag) {
    if (threadIdx.x == 0 && blockIdx.x == 0) {
        int is64 = 1;
        for (int t = 0; t < 64; ++t) {
            if (ei32[2 * t + 1] != 0) { is64 = 0; break; }
        }
        *flag = is64;
    }
}

// ---------------------------------------------------------------------------
// K1: unpack edge_index -> row32/col32 AND per-block coarse-bucket histogram
// (bucket = row >> 7). LDS atomics only; hist[bin*NBLK_C + b] written once.
__global__ __launch_bounds__(TPB_C) void hist_extract_kernel(const void* __restrict__ ei, int E,
                                                             int CH,
                                                             const int* __restrict__ flag,
                                                             int* __restrict__ row32,
                                                             int* __restrict__ col32,
                                                             int* __restrict__ hist,
                                                             int NB, int N) {
    __shared__ int h[MAX_NB];
    int tid = threadIdx.x;
    for (int bin = tid; bin < NB; bin += TPB_C) h[bin] = 0;
    __syncthreads();

    int b = blockIdx.x;
    int s = b * CH;
    int end = min(E, s + CH);
    int is64 = *flag;
    unsigned uN = (unsigned)N;
    if (is64) {
        const long long* p = (const long long*)ei;
        for (int e = s + tid; e < end; e += TPB_C) {
            int r = (int)p[e];
            int c = (int)p[E + e];
            row32[e] = r;
            col32[e] = c;
            if ((unsigned)r < uN && (unsigned)c < uN) atomicAdd(&h[r >> 7], 1);
        }
    } else {
        const int* p = (const int*)ei;
        for (int e = s + tid; e < end; e += TPB_C) {
            int r = p[e];
            int c = p[E + e];
            row32[e] = r;
            col32[e] = c;
            if ((unsigned)r < uN && (unsigned)c < uN) atomicAdd(&h[r >> 7], 1);
        }
    }
    __syncthreads();
    for (int bin = tid; bin < NB; bin += TPB_C) hist[bin * NBLK_C + b] = h[bin];
}

// ---------------------------------------------------------------------------
// K2: per-bucket exclusive scan across the NBLK_C block histograms (in place);
// emits binTotal[bin]. One block per bucket, TPB == NBLK_C.
__global__ __launch_bounds__(NBLK_C) void colscan_kernel(int* __restrict__ hist,
                                                         int* __restrict__ binTotal) {
    __shared__ int sm[NBLK_C];
    int bin = blockIdx.x;
    int tid = threadIdx.x;
    int v = hist[bin * NBLK_C + tid];
    sm[tid] = v;
    __syncthreads();
    for (int o = 1; o < NBLK_C; o <<= 1) {
        int x = (tid >= o) ? sm[tid - o] : 0;
        __syncthreads();
        sm[tid] += x;
        __syncthreads();
    }
    hist[bin * NBLK_C + tid] = sm[tid] - v;  // exclusive within bucket
    if (tid == NBLK_C - 1) binTotal[bin] = sm[NBLK_C - 1];
}

// ---------------------------------------------------------------------------
// K3: exclusive scan over bucket totals -> bucketStart.  NB <= 1024.
__global__ __launch_bounds__(1024) void binscan_kernel(const int* __restrict__ binTotal,
                                                       int* __restrict__ bucketStart, int NB) {
    __shared__ int sm[1024];
    int tid = threadIdx.x;
    int v = (tid < NB) ? binTotal[tid] : 0;
    sm[tid] = v;
    __syncthreads();
    for (int o = 1; o < 1024; o <<= 1) {
        int x = (tid >= o) ? sm[tid - o] : 0;
        __syncthreads();
        sm[tid] += x;
        __syncthreads();
    }
    if (tid < NB) bucketStart[tid] = sm[tid] - v;
}

// ---------------------------------------------------------------------------
// K4: place edges into coarse buckets. Per-block LDS cursors seeded from
// bucketStart + per-block exclusive prefix; packed = (col<<7) | (row&127).
__global__ __launch_bounds__(TPB_C) void scatter_kernel(const int* __restrict__ row32,
                                                        const int* __restrict__ col32, int E,
                                                        int CH,
                                                        const int* __restrict__ hist,
                                                        const int* __restrict__ bucketStart,
                                                        int* __restrict__ bucketed,
                                                        int NB, int N) {
    __shared__ int cur[MAX_NB];
    int tid = threadIdx.x;
    int b = blockIdx.x;
    for (int bin = tid; bin < NB; bin += TPB_C)
        cur[bin] = bucketStart[bin] + hist[bin * NBLK_C + b];
    __syncthreads();

    int s = b * CH;
    int end = min(E, s + CH);
    unsigned uN = (unsigned)N;
    for (int e = s + tid; e < end; e += TPB_C) {
        int r = row32[e];
        int c = col32[e];
        if ((unsigned)r < uN && (unsigned)c < uN) {
            int pos = atomicAdd(&cur[r >> 7], 1);
            bucketed[pos] = (c << 7) | (r & 127);
        }
    }
}

// ---------------------------------------------------------------------------
// K5: fine counting sort inside each 128-row bucket. Emits offs/cnt/dis for
// the bucket's rows and the final csr segment (all LDS atomics).
__global__ __launch_bounds__(TPB) void finecsr_kernel(const int* __restrict__ bucketed,
                                                      const int* __restrict__ bucketStart,
                                                      const int* __restrict__ binTotal,
                                                      int* __restrict__ offs,
                                                      int* __restrict__ cnt,
                                                      float* __restrict__ dis,
                                                      int* __restrict__ csr, int N) {
    __shared__ int c128[128];
    __shared__ int cur128[128];
    __shared__ int sm[TPB];
    int bin = blockIdx.x;
    int tid = threadIdx.x;
    int s = bucketStart[bin];
    int m = binTotal[bin];

    if (tid < 128) c128[tid] = 0;
    __syncthreads();
    for (int i = tid; i < m; i += TPB) atomicAdd(&c128[bucketed[s + i] & 127], 1);
    __syncthreads();

    int v = (tid < 128) ? c128[tid] : 0;
    sm[tid] = v;
    __syncthreads();
    for (int o = 1; o < 128; o <<= 1) {
        int x = (tid >= o) ? sm[tid - o] : 0;
        __syncthreads();
        sm[tid] += x;
        __syncthreads();
    }
    if (tid < 128) {
        int excl = sm[tid] - v;
        int r = bin * 128 + tid;
        if (r < N) {
            offs[r] = s + excl;
            cnt[r] = v;
            dis[r] = rsqrtf((float)v + 1.0f);
        }
        cur128[tid] = s + excl;
    }
    __syncthreads();
    for (int i = tid; i < m; i += TPB) {
        int p = bucketed[s + i];
        int pos = atomicAdd(&cur128[p & 127], 1);
        csr[pos] = p >> 7;
    }
}

// ---------------------------------------------------------------------------
// MFMA bf16 GEMM: Hb[r, :] = bf16( dis[r] * (X[r,:] @ W^T + b) ),  K = 128.
// BM=128 rows/block, BN = 128 or 64 cols. X (fp32 or bf16) and W (fp32) are
// cast to bf16 and staged in LDS with row stride 136 shorts (272 B) so the
// per-fragment ds_read_b128 spreads evenly over all 32 banks.
// 4 waves: BN=128 -> each wave 64x64 (4x4 16x16 tiles); BN=64 -> 32x64 (2x4).
// Fragment layouts (verified, cdna_hip_programming §3):
//   A[m=lane&15][k=(lane>>4)*8+j], B[n=lane&15][k=(lane>>4)*8+j],
//   D: col=lane&15, row=(lane>>4)*4+reg.
template <int BN, bool INB16>
__global__ __launch_bounds__(256, 2) void gemm_mfma_kernel(const void* __restrict__ Xp,
                                                           const float* __restrict__ W,
                                                           const float* __restrict__ bias,
                                                           const float* __restrict__ dis,
                                                           unsigned short* __restrict__ Hb,
                                                           int N) {
    constexpr int XST = 136;  // padded LDS row stride (shorts); 272 B ≡ 4 banks shift/row
    __shared__ unsigned short Xs[128 * XST];
    __shared__ unsigned short Ws[BN * XST];

    const int tid = threadIdx.x;
    const int r0 = blockIdx.x * 128;

    // ---- stage X tile (128 x 128) as bf16
    if (INB16) {
        const ushort4* Xv = (const ushort4*)Xp;
        for (int idx = tid; idx < 128 * 32; idx += 256) {
            int row = idx >> 5, q = idx & 31;
            int rg = r0 + row;
            if (rg >= N) rg = N - 1;
            *(ushort4*)&Xs[row * XST + q * 4] = Xv[(size_t)rg * 32 + q];
        }
    } else {
        const float4* Xv = (const float4*)Xp;
        for (int idx = tid; idx < 128 * 32; idx += 256) {
            int row = idx >> 5, q = idx & 31;
            int rg = r0 + row;
            if (rg >= N) rg = N - 1;
            float4 v = Xv[(size_t)rg * 32 + q];
            ushort4 s = make_ushort4(f2bf(v.x), f2bf(v.y), f2bf(v.z), f2bf(v.w));
            *(ushort4*)&Xs[row * XST + q * 4] = s;
        }
    }
    // ---- stage W tile (BN x 128) as bf16
    {
        const float4* Wv = (const float4*)W;
        for (int idx = tid; idx < BN * 32; idx += 256) {
            int n = idx >> 5, q = idx & 31;
            float4 v = Wv[n * 32 + q];
            ushort4 s = make_ushort4(f2bf(v.x), f2bf(v.y), f2bf(v.z), f2bf(v.w));
            *(ushort4*)&Ws[n * XST + q * 4] = s;
        }
    }
    __syncthreads();

    constexpr int RT = (BN == 128) ? 4 : 2;  // 16-row tiles per wave
    constexpr int CT = 4;                    // 16-col tiles per wave
    const int wave = tid >> 6, lane = tid & 63;
    const int l15 = lane & 15, q8 = lane >> 4;
    const int row0 = (BN == 128) ? (wave & 1) * 64 : wave * 32;
    const int col0 = (BN == 128) ? (wave >> 1) * 64 : 0;

    f32x4 zero = {0.f, 0.f, 0.f, 0.f};
    f32x4 acc[RT][CT];
#pragma unroll
    for (int rt = 0; rt < RT; ++rt)
#pragma unroll
        for (int ct = 0; ct < CT; ++ct) acc[rt][ct] = zero;

#pragma unroll
    for (int ks = 0; ks < 4; ++ks) {
        int ko = ks * 32 + q8 * 8;
        bf16x8 a[RT], b[CT];
#pragma unroll
        for (int rt = 0; rt < RT; ++rt)
            a[rt] = *(const bf16x8*)&Xs[(row0 + rt * 16 + l15) * XST + ko];
#pragma unroll
        for (int ct = 0; ct < CT; ++ct)
            b[ct] = *(const bf16x8*)&Ws[(col0 + ct * 16 + l15) * XST + ko];
#pragma unroll
        for (int rt = 0; rt < RT; ++rt)
#pragma unroll
            for (int ct = 0; ct < CT; ++ct)
                acc[rt][ct] = __builtin_amdgcn_mfma_f32_16x16x32_bf16(
                    a[rt], b[ct], acc[rt][ct], 0, 0, 0);
    }

    // ---- epilogue: (+bias[col]) * dis[row], pack bf16
    float bv[CT];
#pragma unroll
    for (int ct = 0; ct < CT; ++ct) bv[ct] = bias[col0 + ct * 16 + l15];
#pragma unroll
    for (int rt = 0; rt < RT; ++rt)
#pragma unroll
        for (int r = 0; r < 4; ++r) {
            int row = r0 + row0 + rt * 16 + q8 * 4 + r;
            if (row < N) {
                float dn = dis[row];
#pragma unroll
                for (int ct = 0; ct < CT; ++ct)
                    Hb[(size_t)row * BN + col0 + ct * 16 + l15] =
                        f2bf((acc[rt][ct][r] + bv[ct]) * dn);
            }
        }
}

// ---------------------------------------------------------------------------
// Pull aggregation over pre-scaled bf16 H' (H'[n] = dis[n]*(XW+b)[n]):
//   out[i] = dis[i] * (H'[i] + sum_e H'[col_e]),  optional relu.
// OB16: pack output to bf16 (for R1 feeding the bf16 MFMA gemm2).
template <int F, bool RELU, bool OB16>
__global__ __launch_bounds__(TPB) void agg_kernel(const unsigned short* __restrict__ Hb,
                                                  const int* __restrict__ csr,
                                                  const int* __restrict__ offs,
                                                  const int* __restrict__ cnt,
                                                  const float* __restrict__ dis,
                                                  void* __restrict__ outp, int N) {
    int w = (blockIdx.x * TPB + threadIdx.x) >> 6;
    if (w >= N) return;  // wave-uniform: whole wave exits together
    int lane = threadIdx.x & 63;
    float di = dis[w];
    int s = offs[w];
    int d = cnt[w];

    const unsigned* Hu = (const unsigned*)Hb;
    float2 acc;
    if (F == 128) {
        unsigned u = Hu[w * 64 + lane];
        acc.x = bf16lo(u);
        acc.y = bf16hi(u);
    } else {
        acc.x = __uint_as_float(((unsigned)Hb[w * 64 + lane]) << 16);
        acc.y = 0.0f;
    }

    for (int base = 0; base < d; base += 64) {
        int rem = d - base;
        if (rem > 64) rem = 64;
        int cl = (lane < rem) ? csr[s + base + lane] : 0;  // coalesced chunk load

        int e = 0;
        for (; e + 8 <= rem; e += 8) {
            int c0 = __shfl(cl, e + 0);
            int c1 = __shfl(cl, e + 1);
            int c2 = __shfl(cl, e + 2);
            int c3 = __shfl(cl, e + 3);
            int c4 = __shfl(cl, e + 4);
            int c5 = __shfl(cl, e + 5);
            int c6 = __shfl(cl, e + 6);
            int c7 = __shfl(cl, e + 7);
            if (F == 128) {
                unsigned u0 = Hu[c0 * 64 + lane];
                unsigned u1 = Hu[c1 * 64 + lane];
                unsigned u2 = Hu[c2 * 64 + lane];
                unsigned u3 = Hu[c3 * 64 + lane];
                unsigned u4 = Hu[c4 * 64 + lane];
                unsigned u5 = Hu[c5 * 64 + lane];
                unsigned u6 = Hu[c6 * 64 + lane];
                unsigned u7 = Hu[c7 * 64 + lane];
                acc.x += ((bf16lo(u0) + bf16lo(u1)) + (bf16lo(u2) + bf16lo(u3))) +
                         ((bf16lo(u4) + bf16lo(u5)) + (bf16lo(u6) + bf16lo(u7)));
                acc.y += ((bf16hi(u0) + bf16hi(u1)) + (bf16hi(u2) + bf16hi(u3))) +
                         ((bf16hi(u4) + bf16hi(u5)) + (bf16hi(u6) + bf16hi(u7)));
            } else {
                float h0 = __uint_as_float(((unsigned)Hb[c0 * 64 + lane]) << 16);
                float h1 = __uint_as_float(((unsigned)Hb[c1 * 64 + lane]) << 16);
                float h2 = __uint_as_float(((unsigned)Hb[c2 * 64 + lane]) << 16);
                float h3 = __uint_as_float(((unsigned)Hb[c3 * 64 + lane]) << 16);
                float h4 = __uint_as_float(((unsigned)Hb[c4 * 64 + lane]) << 16);
                float h5 = __uint_as_float(((unsigned)Hb[c5 * 64 + lane]) << 16);
                float h6 = __uint_as_float(((unsigned)Hb[c6 * 64 + lane]) << 16);
                float h7 = __uint_as_float(((unsigned)Hb[c7 * 64 + lane]) << 16);
                acc.x += ((h0 + h1) + (h2 + h3)) + ((h4 + h5) + (h6 + h7));
            }
        }
        for (; e < rem; ++e) {
            int c0 = __shfl(cl, e);
            if (F == 128) {
                unsigned u0 = Hu[c0 * 64 + lane];
                acc.x += bf16lo(u0);
                acc.y += bf16hi(u0);
            } else {
                acc.x += __uint_as_float(((unsigned)Hb[c0 * 64 + lane]) << 16);
            }
        }
    }

    acc.x *= di;
    acc.y *= di;
    if (RELU) { acc.x = fmaxf(acc.x, 0.f); acc.y = fmaxf(acc.y, 0.f); }
    if (OB16) {
        unsigned lo = f2bf(acc.x), hi = f2bf(acc.y);
        ((unsigned*)outp)[w * 64 + lane] = lo | (hi << 16);  // cols 2*lane, 2*lane+1
    } else if (F == 128) {
        ((float2*)outp)[w * 64 + lane] = acc;
    } else {
        ((float*)outp)[w * 64 + lane] = acc.x;
    }
}

// ---------------------------------------------------------------------------
extern "C" void kernel_launch(void* const* d_in, const int* in_sizes, int n_in,
                              void* d_out, int out_size, void* d_ws, size_t ws_size,
                              hipStream_t stream) {
    const float* x  = (const float*)d_in[0];
    const void*  ei = d_in[1];
    const float* W1 = (const float*)d_in[3];
    const float* b1 = (const float*)d_in[4];
    const float* W2 = (const float*)d_in[5];
    const float* b2 = (const float*)d_in[6];
    float* out = (float*)d_out;

    const int IN = 128, HID = 128;
    const int N = in_sizes[0] / IN;
    const int E = in_sizes[1] / 2;
    const int NB = (N + 127) >> 7;                 // coarse buckets (rows/128)
    const int CH = (E + NBLK_C - 1) / NBLK_C;      // edges per chunk block

    char* ws = (char*)d_ws;
    size_t off = 0;
    auto alloc = [&](size_t bytes) -> void* {
        void* p = (void*)(ws + off);
        off += (bytes + 255) & ~(size_t)255;
        return p;
    };
    int*   flag     = (int*)alloc(256);
    int*   cnt      = (int*)alloc((size_t)N * 4);
    int*   offs     = (int*)alloc((size_t)N * 4);
    float* dis      = (float*)alloc((size_t)N * 4);
    int*   row32    = (int*)alloc((size_t)E * 4);
    int*   col32    = (int*)alloc((size_t)E * 4);
    int*   bucketed = (int*)alloc((size_t)E * 4);
    int*   csr      = (int*)alloc((size_t)E * 4);
    int*   hist     = (int*)alloc((size_t)NB * NBLK_C * 4);
    int*   binTotal = (int*)alloc((size_t)NB * 4);
    int*   bStart   = (int*)alloc((size_t)NB * 4);
    unsigned short* H1b = (unsigned short*)alloc((size_t)N * HID * 2);  // bf16
    unsigned short* R1b = (unsigned short*)alloc((size_t)N * HID * 2);  // bf16
    unsigned short* H2b = H1b;  // reuse: H1b dead after agg1

    detect64_kernel<<<1, 64, 0, stream>>>((const int*)ei, flag);

    // ---- CSR build: counting sort, zero global atomics
    hist_extract_kernel<<<NBLK_C, TPB_C, 0, stream>>>(ei, E, CH, flag, row32, col32,
                                                      hist, NB, N);
    colscan_kernel<<<NB, NBLK_C, 0, stream>>>(hist, binTotal);
    binscan_kernel<<<1, 1024, 0, stream>>>(binTotal, bStart, NB);
    scatter_kernel<<<NBLK_C, TPB_C, 0, stream>>>(row32, col32, E, CH, hist, bStart,
                                                 bucketed, NB, N);
    finecsr_kernel<<<NB, TPB, 0, stream>>>(bucketed, bStart, binTotal,
                                           offs, cnt, dis, csr, N);

    int ngrid = (N + 127) / 128;

    // layer 1: H1b = bf16(dis .* (X@W1^T + b1)) ; R1b = bf16(relu(dis .* (self+gather)))
    gemm_mfma_kernel<128, false><<<ngrid, 256, 0, stream>>>(x, W1, b1, dis, H1b, N);
    agg_kernel<128, true, true><<<(N + 3) / 4, TPB, 0, stream>>>(H1b, csr, offs, cnt,
                                                                 dis, R1b, N);

    // layer 2: H2b = bf16(dis .* (R1b@W2^T + b2)) ; out = dis .* (self + gather)
    gemm_mfma_kernel<64, true><<<ngrid, 256, 0, stream>>>(R1b, W2, b2, dis, H2b, N);
    agg_kernel<64, false, false><<<(N + 3) / 4, TPB, 0, stream>>>(H2b, csr, offs, cnt,
                                                                  dis, out, N);
}